// Round 3
// baseline (209.094 us; speedup 1.0000x reference)
//
#include <hip/hip_runtime.h>

#define KEHALF 7.199822675975274f
#define CUTOFF 12.0f

typedef float fx4 __attribute__((ext_vector_type(4)));
typedef int   ix4 __attribute__((ext_vector_type(4)));

__global__ __launch_bounds__(256)
void damped_elec_kernel(const float* __restrict__ dist,
                        const float* __restrict__ vec,
                        const float* __restrict__ q,
                        const float* __restrict__ mu,
                        const float* __restrict__ quad,
                        const int* __restrict__ idx_u,
                        const int* __restrict__ idx_v,
                        float* __restrict__ out,
                        int E) {
    int t = blockIdx.x * blockDim.x + threadIdx.x;
    int e0 = t * 4;
    if (e0 >= E) return;

    if (e0 + 4 <= E) {
        // ---- Phase 0: streaming loads (non-temporal: don't pollute L2) ----
        fx4 d4 = __builtin_nontemporal_load(reinterpret_cast<const fx4*>(dist + e0));
        ix4 u4 = __builtin_nontemporal_load(reinterpret_cast<const ix4*>(idx_u + e0));
        ix4 v4 = __builtin_nontemporal_load(reinterpret_cast<const ix4*>(idx_v + e0));
        fx4 va = __builtin_nontemporal_load(reinterpret_cast<const fx4*>(vec + 3 * e0));
        fx4 vb = __builtin_nontemporal_load(reinterpret_cast<const fx4*>(vec + 3 * e0 + 4));
        fx4 vc = __builtin_nontemporal_load(reinterpret_cast<const fx4*>(vec + 3 * e0 + 8));

        float db[4]  = {d4.x, d4.y, d4.z, d4.w};
        int   ub[4]  = {u4.x, u4.y, u4.z, u4.w};
        int   vb2[4] = {v4.x, v4.y, v4.z, v4.w};
        float vvv[12] = {va.x, va.y, va.z, va.w,
                         vb.x, vb.y, vb.z, vb.w,
                         vc.x, vc.y, vc.z, vc.w};

        // ---- Phase 1: issue ALL gathers up front (28 scattered loads in flight) ----
        float quf[4], qvf[4];
        float muu[4][3], muv[4][3], Q[4][9];
#pragma unroll
        for (int k = 0; k < 4; ++k) {
            int u = ub[k], v = vb2[k];
            quf[k] = q[u];
            qvf[k] = q[v];
            const float* pu = mu + 3 * u;
            const float* pv = mu + 3 * v;
            const float* pq = quad + 9 * v;
#pragma unroll
            for (int j = 0; j < 3; ++j) { muu[k][j] = pu[j]; muv[k][j] = pv[j]; }
#pragma unroll
            for (int j = 0; j < 9; ++j) Q[k][j] = pq[j];
        }

        // ---- Phase 2: compute ----
        float res[4];
#pragma unroll
        for (int k = 0; k < 4; ++k) {
            float d = db[k];
            float vx = vvv[3 * k + 0], vy = vvv[3 * k + 1], vz = vvv[3 * k + 2];

            float inv_d = __builtin_amdgcn_rcpf(d);
            float x = fminf(fmaxf(d * 0.5f, 0.0f), 1.0f);
            float x2 = x * x;
            float x3 = x2 * x;
            float sw = 1.0f - x3 * (10.0f - 15.0f * x + 6.0f * x2);
            float chi = sw * __builtin_amdgcn_rsqf(d * d + 1.0f) + (1.0f - sw) * inv_d;
            float chi2 = chi * chi;
            float chi3 = chi2 * chi;

            float dot_uv = (vx * muv[k][0] + vy * muv[k][1] + vz * muv[k][2]) * inv_d;
            float dot_vu = (vx * muu[k][0] + vy * muu[k][1] + vz * muu[k][2]) * inv_d;
            float mudot  = muu[k][0] * muv[k][0] + muu[k][1] * muv[k][1] + muu[k][2] * muv[k][2];

            float Eelec = quf[k] * qvf[k] * chi
                        + 2.0f * quf[k] * dot_uv * chi2
                        + (mudot - 3.0f * dot_uv * dot_vu) * chi3;

            float s = vx * (vx * Q[k][0] + vy * Q[k][1] + vz * Q[k][2])
                    + vy * (vx * Q[k][3] + vy * Q[k][4] + vz * Q[k][5])
                    + vz * (vx * Q[k][6] + vy * Q[k][7] + vz * Q[k][8]);
            float tr = Q[k][0] + Q[k][4] + Q[k][8];
            float n2 = vx * vx + vy * vy + vz * vz;
            float sum_uv = (s - n2 * (1.0f / 3.0f) * tr) * (inv_d * inv_d);

            Eelec += quf[k] * sum_uv * chi3;
            res[k] = (d <= CUTOFF) ? (KEHALF * Eelec) : 0.0f;
        }
        fx4 o4 = {res[0], res[1], res[2], res[3]};
        __builtin_nontemporal_store(o4, reinterpret_cast<fx4*>(out + e0));
    } else {
        // Scalar tail (E % 4 != 0 only).
        for (int e = e0; e < E; ++e) {
            float d = dist[e];
            int u = idx_u[e], v = idx_v[e];
            float vx = vec[3 * e + 0], vy = vec[3 * e + 1], vz = vec[3 * e + 2];

            float inv_d = 1.0f / d;
            float x = fminf(fmaxf(d * 0.5f, 0.0f), 1.0f);
            float x2 = x * x;
            float x3 = x2 * x;
            float sw = 1.0f - x3 * (10.0f - 15.0f * x + 6.0f * x2);
            float chi = sw / sqrtf(d * d + 1.0f) + (1.0f - sw) * inv_d;
            float chi2 = chi * chi;
            float chi3 = chi2 * chi;

            float qu = q[u], qv = q[v];
            const float* mu_u = mu + 3 * u;
            const float* mu_v = mu + 3 * v;
            float dot_uv = (vx * mu_v[0] + vy * mu_v[1] + vz * mu_v[2]) * inv_d;
            float dot_vu = (vx * mu_u[0] + vy * mu_u[1] + vz * mu_u[2]) * inv_d;
            float mudot  = mu_u[0] * mu_v[0] + mu_u[1] * mu_v[1] + mu_u[2] * mu_v[2];

            float Eelec = qu * qv * chi
                        + 2.0f * qu * dot_uv * chi2
                        + (mudot - 3.0f * dot_uv * dot_vu) * chi3;

            const float* Qv = quad + 9 * v;
            float s = vx * (vx * Qv[0] + vy * Qv[1] + vz * Qv[2])
                    + vy * (vx * Qv[3] + vy * Qv[4] + vz * Qv[5])
                    + vz * (vx * Qv[6] + vy * Qv[7] + vz * Qv[8]);
            float tr = Qv[0] + Qv[4] + Qv[8];
            float n2 = vx * vx + vy * vy + vz * vz;
            float sum_uv = (s - n2 * (1.0f / 3.0f) * tr) * (inv_d * inv_d);

            Eelec += qu * sum_uv * chi3;
            out[e] = (d <= CUTOFF) ? (KEHALF * Eelec) : 0.0f;
        }
    }
}

extern "C" void kernel_launch(void* const* d_in, const int* in_sizes, int n_in,
                              void* d_out, int out_size, void* d_ws, size_t ws_size,
                              hipStream_t stream) {
    const float* dist  = (const float*)d_in[0];
    const float* vec   = (const float*)d_in[1];
    const float* q     = (const float*)d_in[2];
    const float* mu    = (const float*)d_in[3];
    const float* quad  = (const float*)d_in[4];
    const int*   idx_u = (const int*)d_in[5];
    const int*   idx_v = (const int*)d_in[6];
    float* out = (float*)d_out;

    int E = in_sizes[0];
    int threads = (E + 3) / 4;
    int block = 256;
    int grid = (threads + block - 1) / block;
    damped_elec_kernel<<<grid, block, 0, stream>>>(dist, vec, q, mu, quad,
                                                   idx_u, idx_v, out, E);
}

// Round 4
// 187.936 us; speedup vs baseline: 1.1126x; 1.1126x over previous
//
#include <hip/hip_runtime.h>

#define KEHALF 7.199822675975274f
#define CUTOFF 12.0f

typedef float fx4 __attribute__((ext_vector_type(4)));
typedef int   ix4 __attribute__((ext_vector_type(4)));

// ---- Pack kernel: T[atom] = 16 floats (one 64B line): [q, mu(3), Q(9), pad(3)] ----
__global__ __launch_bounds__(256)
void pack_atoms_kernel(const float* __restrict__ q,
                       const float* __restrict__ mu,
                       const float* __restrict__ quad,
                       float* __restrict__ T, int N) {
    int a = blockIdx.x * blockDim.x + threadIdx.x;
    if (a >= N) return;
    const float* m = mu + 3 * a;
    const float* Q = quad + 9 * a;
    fx4 t0 = {q[a], m[0], m[1], m[2]};
    fx4 t1 = {Q[0], Q[1], Q[2], Q[3]};
    fx4 t2 = {Q[4], Q[5], Q[6], Q[7]};
    fx4 t3 = {Q[8], 0.0f, 0.0f, 0.0f};
    fx4* dst = reinterpret_cast<fx4*>(T + 16 * a);
    dst[0] = t0; dst[1] = t1; dst[2] = t2; dst[3] = t3;
}

// ---- Main kernel: packed-table gathers (2 lines / 5 loads per edge) ----
__global__ __launch_bounds__(256)
void damped_elec_packed(const float* __restrict__ dist,
                        const float* __restrict__ vec,
                        const float* __restrict__ T,
                        const int* __restrict__ idx_u,
                        const int* __restrict__ idx_v,
                        float* __restrict__ out, int E) {
    int t = blockIdx.x * blockDim.x + threadIdx.x;
    int e0 = t * 4;
    if (e0 >= E) return;

    if (e0 + 4 <= E) {
        // Streaming loads (non-temporal).
        fx4 d4 = __builtin_nontemporal_load(reinterpret_cast<const fx4*>(dist + e0));
        ix4 u4 = __builtin_nontemporal_load(reinterpret_cast<const ix4*>(idx_u + e0));
        ix4 v4 = __builtin_nontemporal_load(reinterpret_cast<const ix4*>(idx_v + e0));
        fx4 va = __builtin_nontemporal_load(reinterpret_cast<const fx4*>(vec + 3 * e0));
        fx4 vb = __builtin_nontemporal_load(reinterpret_cast<const fx4*>(vec + 3 * e0 + 4));
        fx4 vc = __builtin_nontemporal_load(reinterpret_cast<const fx4*>(vec + 3 * e0 + 8));

        float db[4]  = {d4.x, d4.y, d4.z, d4.w};
        int   ub[4]  = {u4.x, u4.y, u4.z, u4.w};
        int   vbi[4] = {v4.x, v4.y, v4.z, v4.w};
        float vvv[12] = {va.x, va.y, va.z, va.w,
                         vb.x, vb.y, vb.z, vb.w,
                         vc.x, vc.y, vc.z, vc.w};

        // Gather phase: 5 vector loads per edge, all issued up front.
        fx4 Au[4], Bv0[4], Bv1[4], Bv2[4];
        float q22[4];
#pragma unroll
        for (int k = 0; k < 4; ++k) {
            const fx4* pu = reinterpret_cast<const fx4*>(T + 16 * (long)ub[k]);
            const fx4* pv = reinterpret_cast<const fx4*>(T + 16 * (long)vbi[k]);
            Au[k]  = pu[0];
            Bv0[k] = pv[0];
            Bv1[k] = pv[1];
            Bv2[k] = pv[2];
            q22[k] = T[16 * (long)vbi[k] + 12];
        }

        // Compute phase.
        float res[4];
#pragma unroll
        for (int k = 0; k < 4; ++k) {
            float d = db[k];
            float vx = vvv[3 * k + 0], vy = vvv[3 * k + 1], vz = vvv[3 * k + 2];

            float inv_d = __builtin_amdgcn_rcpf(d);
            float x = fminf(fmaxf(d * 0.5f, 0.0f), 1.0f);
            float x2 = x * x;
            float x3 = x2 * x;
            float sw = 1.0f - x3 * (10.0f - 15.0f * x + 6.0f * x2);
            float chi = sw * __builtin_amdgcn_rsqf(d * d + 1.0f) + (1.0f - sw) * inv_d;
            float chi2 = chi * chi;
            float chi3 = chi2 * chi;

            float qu = Au[k].x;
            float mux_u = Au[k].y, muy_u = Au[k].z, muz_u = Au[k].w;
            float qv = Bv0[k].x;
            float mux_v = Bv0[k].y, muy_v = Bv0[k].z, muz_v = Bv0[k].w;
            // Q row-major: q00 q01 q02 / q10 q11 q12 / q20 q21 q22
            float q00 = Bv1[k].x, q01 = Bv1[k].y, q02 = Bv1[k].z, q10 = Bv1[k].w;
            float q11 = Bv2[k].x, q12 = Bv2[k].y, q20 = Bv2[k].z, q21 = Bv2[k].w;

            float dot_uv = (vx * mux_v + vy * muy_v + vz * muz_v) * inv_d;
            float dot_vu = (vx * mux_u + vy * muy_u + vz * muz_u) * inv_d;
            float mudot  = mux_u * mux_v + muy_u * muy_v + muz_u * muz_v;

            float Eelec = qu * qv * chi
                        + 2.0f * qu * dot_uv * chi2
                        + (mudot - 3.0f * dot_uv * dot_vu) * chi3;

            float s = vx * (vx * q00 + vy * q01 + vz * q02)
                    + vy * (vx * q10 + vy * q11 + vz * q12)
                    + vz * (vx * q20 + vy * q21 + vz * q22[k]);
            float tr = q00 + q11 + q22[k];
            float n2 = vx * vx + vy * vy + vz * vz;
            float sum_uv = (s - n2 * (1.0f / 3.0f) * tr) * (inv_d * inv_d);

            Eelec += qu * sum_uv * chi3;
            res[k] = (d <= CUTOFF) ? (KEHALF * Eelec) : 0.0f;
        }
        fx4 o4 = {res[0], res[1], res[2], res[3]};
        __builtin_nontemporal_store(o4, reinterpret_cast<fx4*>(out + e0));
    } else {
        for (int e = e0; e < E; ++e) {
            float d = dist[e];
            int u = idx_u[e], v = idx_v[e];
            float vx = vec[3 * e + 0], vy = vec[3 * e + 1], vz = vec[3 * e + 2];
            const float* Tu = T + 16 * (long)u;
            const float* Tv = T + 16 * (long)v;

            float inv_d = 1.0f / d;
            float x = fminf(fmaxf(d * 0.5f, 0.0f), 1.0f);
            float x2 = x * x, x3 = x2 * x;
            float sw = 1.0f - x3 * (10.0f - 15.0f * x + 6.0f * x2);
            float chi = sw / sqrtf(d * d + 1.0f) + (1.0f - sw) * inv_d;
            float chi2 = chi * chi, chi3 = chi2 * chi;

            float qu = Tu[0], qv = Tv[0];
            float dot_uv = (vx * Tv[1] + vy * Tv[2] + vz * Tv[3]) * inv_d;
            float dot_vu = (vx * Tu[1] + vy * Tu[2] + vz * Tu[3]) * inv_d;
            float mudot  = Tu[1] * Tv[1] + Tu[2] * Tv[2] + Tu[3] * Tv[3];

            float Eelec = qu * qv * chi
                        + 2.0f * qu * dot_uv * chi2
                        + (mudot - 3.0f * dot_uv * dot_vu) * chi3;

            float s = vx * (vx * Tv[4] + vy * Tv[5] + vz * Tv[6])
                    + vy * (vx * Tv[7] + vy * Tv[8] + vz * Tv[9])
                    + vz * (vx * Tv[10] + vy * Tv[11] + vz * Tv[12]);
            float tr = Tv[4] + Tv[8] + Tv[12];
            float n2 = vx * vx + vy * vy + vz * vz;
            float sum_uv = (s - n2 * (1.0f / 3.0f) * tr) * (inv_d * inv_d);

            Eelec += qu * sum_uv * chi3;
            out[e] = (d <= CUTOFF) ? (KEHALF * Eelec) : 0.0f;
        }
    }
}

// ---- Fallback (ws too small): direct scalar-gather kernel ----
__global__ __launch_bounds__(256)
void damped_elec_direct(const float* __restrict__ dist,
                        const float* __restrict__ vec,
                        const float* __restrict__ q,
                        const float* __restrict__ mu,
                        const float* __restrict__ quad,
                        const int* __restrict__ idx_u,
                        const int* __restrict__ idx_v,
                        float* __restrict__ out, int E) {
    int e = blockIdx.x * blockDim.x + threadIdx.x;
    if (e >= E) return;
    float d = dist[e];
    int u = idx_u[e], v = idx_v[e];
    float vx = vec[3 * e + 0], vy = vec[3 * e + 1], vz = vec[3 * e + 2];

    float inv_d = 1.0f / d;
    float x = fminf(fmaxf(d * 0.5f, 0.0f), 1.0f);
    float x2 = x * x, x3 = x2 * x;
    float sw = 1.0f - x3 * (10.0f - 15.0f * x + 6.0f * x2);
    float chi = sw / sqrtf(d * d + 1.0f) + (1.0f - sw) * inv_d;
    float chi2 = chi * chi, chi3 = chi2 * chi;

    float qu = q[u], qv = q[v];
    const float* mu_u = mu + 3 * u;
    const float* mu_v = mu + 3 * v;
    float dot_uv = (vx * mu_v[0] + vy * mu_v[1] + vz * mu_v[2]) * inv_d;
    float dot_vu = (vx * mu_u[0] + vy * mu_u[1] + vz * mu_u[2]) * inv_d;
    float mudot  = mu_u[0] * mu_v[0] + mu_u[1] * mu_v[1] + mu_u[2] * mu_v[2];

    float Eelec = qu * qv * chi
                + 2.0f * qu * dot_uv * chi2
                + (mudot - 3.0f * dot_uv * dot_vu) * chi3;

    const float* Qv = quad + 9 * v;
    float s = vx * (vx * Qv[0] + vy * Qv[1] + vz * Qv[2])
            + vy * (vx * Qv[3] + vy * Qv[4] + vz * Qv[5])
            + vz * (vx * Qv[6] + vy * Qv[7] + vz * Qv[8]);
    float tr = Qv[0] + Qv[4] + Qv[8];
    float n2 = vx * vx + vy * vy + vz * vz;
    float sum_uv = (s - n2 * (1.0f / 3.0f) * tr) * (inv_d * inv_d);

    Eelec += qu * sum_uv * chi3;
    out[e] = (d <= CUTOFF) ? (KEHALF * Eelec) : 0.0f;
}

extern "C" void kernel_launch(void* const* d_in, const int* in_sizes, int n_in,
                              void* d_out, int out_size, void* d_ws, size_t ws_size,
                              hipStream_t stream) {
    const float* dist  = (const float*)d_in[0];
    const float* vec   = (const float*)d_in[1];
    const float* q     = (const float*)d_in[2];
    const float* mu    = (const float*)d_in[3];
    const float* quad  = (const float*)d_in[4];
    const int*   idx_u = (const int*)d_in[5];
    const int*   idx_v = (const int*)d_in[6];
    float* out = (float*)d_out;

    int E = in_sizes[0];
    int N = in_sizes[2];  // atomic_charges count == N_ATOMS

    size_t need = (size_t)N * 16 * sizeof(float);
    if (ws_size >= need) {
        float* T = (float*)d_ws;
        int pb = 256;
        pack_atoms_kernel<<<(N + pb - 1) / pb, pb, 0, stream>>>(q, mu, quad, T, N);
        int threads = (E + 3) / 4;
        damped_elec_packed<<<(threads + 255) / 256, 256, 0, stream>>>(
            dist, vec, T, idx_u, idx_v, out, E);
    } else {
        damped_elec_direct<<<(E + 255) / 256, 256, 0, stream>>>(
            dist, vec, q, mu, quad, idx_u, idx_v, out, E);
    }
}

// Round 5
// 164.058 us; speedup vs baseline: 1.2745x; 1.1455x over previous
//
#include <hip/hip_runtime.h>

#define KEHALF 7.199822675975274f
#define CUTOFF 12.0f

typedef float    fx4 __attribute__((ext_vector_type(4)));
typedef int      ix4 __attribute__((ext_vector_type(4)));
typedef _Float16 hx4 __attribute__((ext_vector_type(4)));
typedef _Float16 hx8 __attribute__((ext_vector_type(8)));

// ---- Pack kernel: T[atom] = 16 halves (32B): [q, mu(3), Q(9), pad(3)] ----
// Table = 100K * 32B = 3.2 MB -> fits a 4 MB per-XCD L2.
__global__ __launch_bounds__(256)
void pack_atoms_half(const float* __restrict__ q,
                     const float* __restrict__ mu,
                     const float* __restrict__ quad,
                     _Float16* __restrict__ T, int N) {
    int a = blockIdx.x * blockDim.x + threadIdx.x;
    if (a >= N) return;
    const float* m = mu + 3 * a;
    const float* Q = quad + 9 * a;
    hx8 t0, t1;
    t0[0] = (_Float16)q[a];
    t0[1] = (_Float16)m[0]; t0[2] = (_Float16)m[1]; t0[3] = (_Float16)m[2];
    t0[4] = (_Float16)Q[0]; t0[5] = (_Float16)Q[1]; t0[6] = (_Float16)Q[2]; t0[7] = (_Float16)Q[3];
    t1[0] = (_Float16)Q[4]; t1[1] = (_Float16)Q[5]; t1[2] = (_Float16)Q[6]; t1[3] = (_Float16)Q[7];
    t1[4] = (_Float16)Q[8]; t1[5] = (_Float16)0.0f; t1[6] = (_Float16)0.0f; t1[7] = (_Float16)0.0f;
    hx8* dst = reinterpret_cast<hx8*>(T + 16 * a);
    dst[0] = t0; dst[1] = t1;
}

// ---- Main kernel: fp16-table gathers (3 loads / 40B per edge, L2-resident) ----
__global__ __launch_bounds__(256, 4)
void damped_elec_h(const float* __restrict__ dist,
                   const float* __restrict__ vec,
                   const _Float16* __restrict__ T,
                   const int* __restrict__ idx_u,
                   const int* __restrict__ idx_v,
                   float* __restrict__ out, int E) {
    int t = blockIdx.x * blockDim.x + threadIdx.x;
    int e0 = t * 4;
    if (e0 >= E) return;

    if (e0 + 4 <= E) {
        // Streaming loads (non-temporal: keep L2 for the atom table).
        fx4 d4 = __builtin_nontemporal_load(reinterpret_cast<const fx4*>(dist + e0));
        ix4 u4 = __builtin_nontemporal_load(reinterpret_cast<const ix4*>(idx_u + e0));
        ix4 v4 = __builtin_nontemporal_load(reinterpret_cast<const ix4*>(idx_v + e0));
        fx4 va = __builtin_nontemporal_load(reinterpret_cast<const fx4*>(vec + 3 * e0));
        fx4 vb = __builtin_nontemporal_load(reinterpret_cast<const fx4*>(vec + 3 * e0 + 4));
        fx4 vc = __builtin_nontemporal_load(reinterpret_cast<const fx4*>(vec + 3 * e0 + 8));

        float db[4]  = {d4.x, d4.y, d4.z, d4.w};
        int   ub[4]  = {u4.x, u4.y, u4.z, u4.w};
        int   vbi[4] = {v4.x, v4.y, v4.z, v4.w};
        float vvv[12] = {va.x, va.y, va.z, va.w,
                         vb.x, vb.y, vb.z, vb.w,
                         vc.x, vc.y, vc.z, vc.w};

        // Gather phase: 3 loads per edge, small dst footprint (10 VGPR/edge).
        hx4 au[4];
        hx8 bv0[4], bv1[4];
#pragma unroll
        for (int k = 0; k < 4; ++k) {
            int ou = ub[k] << 4;   // 16 halves per atom
            int ov = vbi[k] << 4;
            au[k]  = *reinterpret_cast<const hx4*>(T + ou);
            bv0[k] = *reinterpret_cast<const hx8*>(T + ov);
            bv1[k] = *reinterpret_cast<const hx8*>(T + ov + 8);
        }

        // Compute phase (fp32).
        float res[4];
#pragma unroll
        for (int k = 0; k < 4; ++k) {
            float d = db[k];
            float vx = vvv[3 * k + 0], vy = vvv[3 * k + 1], vz = vvv[3 * k + 2];

            float inv_d = __builtin_amdgcn_rcpf(d);
            float x = fminf(fmaxf(d * 0.5f, 0.0f), 1.0f);
            float x2 = x * x;
            float x3 = x2 * x;
            float sw = 1.0f - x3 * (10.0f - 15.0f * x + 6.0f * x2);
            float chi = sw * __builtin_amdgcn_rsqf(d * d + 1.0f) + (1.0f - sw) * inv_d;
            float chi2 = chi * chi;
            float chi3 = chi2 * chi;

            float qu    = (float)au[k][0];
            float mux_u = (float)au[k][1], muy_u = (float)au[k][2], muz_u = (float)au[k][3];
            float qv    = (float)bv0[k][0];
            float mux_v = (float)bv0[k][1], muy_v = (float)bv0[k][2], muz_v = (float)bv0[k][3];
            float q00 = (float)bv0[k][4], q01 = (float)bv0[k][5], q02 = (float)bv0[k][6];
            float q10 = (float)bv0[k][7];
            float q11 = (float)bv1[k][0], q12 = (float)bv1[k][1], q20 = (float)bv1[k][2];
            float q21 = (float)bv1[k][3], q22 = (float)bv1[k][4];

            float dot_uv = (vx * mux_v + vy * muy_v + vz * muz_v) * inv_d;
            float dot_vu = (vx * mux_u + vy * muy_u + vz * muz_u) * inv_d;
            float mudot  = mux_u * mux_v + muy_u * muy_v + muz_u * muz_v;

            float Eelec = qu * qv * chi
                        + 2.0f * qu * dot_uv * chi2
                        + (mudot - 3.0f * dot_uv * dot_vu) * chi3;

            float s = vx * (vx * q00 + vy * q01 + vz * q02)
                    + vy * (vx * q10 + vy * q11 + vz * q12)
                    + vz * (vx * q20 + vy * q21 + vz * q22);
            float tr = q00 + q11 + q22;
            float n2 = vx * vx + vy * vy + vz * vz;
            float sum_uv = (s - n2 * (1.0f / 3.0f) * tr) * (inv_d * inv_d);

            Eelec += qu * sum_uv * chi3;
            res[k] = (d <= CUTOFF) ? (KEHALF * Eelec) : 0.0f;
        }
        fx4 o4 = {res[0], res[1], res[2], res[3]};
        __builtin_nontemporal_store(o4, reinterpret_cast<fx4*>(out + e0));
    } else {
        // Scalar tail.
        for (int e = e0; e < E; ++e) {
            float d = dist[e];
            int u = idx_u[e], v = idx_v[e];
            float vx = vec[3 * e + 0], vy = vec[3 * e + 1], vz = vec[3 * e + 2];
            const _Float16* Tu = T + (u << 4);
            const _Float16* Tv = T + (v << 4);

            float inv_d = 1.0f / d;
            float x = fminf(fmaxf(d * 0.5f, 0.0f), 1.0f);
            float x2 = x * x, x3 = x2 * x;
            float sw = 1.0f - x3 * (10.0f - 15.0f * x + 6.0f * x2);
            float chi = sw / sqrtf(d * d + 1.0f) + (1.0f - sw) * inv_d;
            float chi2 = chi * chi, chi3 = chi2 * chi;

            float qu = (float)Tu[0], qv = (float)Tv[0];
            float dot_uv = (vx * (float)Tv[1] + vy * (float)Tv[2] + vz * (float)Tv[3]) * inv_d;
            float dot_vu = (vx * (float)Tu[1] + vy * (float)Tu[2] + vz * (float)Tu[3]) * inv_d;
            float mudot  = (float)Tu[1] * (float)Tv[1] + (float)Tu[2] * (float)Tv[2]
                         + (float)Tu[3] * (float)Tv[3];

            float Eelec = qu * qv * chi
                        + 2.0f * qu * dot_uv * chi2
                        + (mudot - 3.0f * dot_uv * dot_vu) * chi3;

            float s = vx * (vx * (float)Tv[4] + vy * (float)Tv[5] + vz * (float)Tv[6])
                    + vy * (vx * (float)Tv[7] + vy * (float)Tv[8] + vz * (float)Tv[9])
                    + vz * (vx * (float)Tv[10] + vy * (float)Tv[11] + vz * (float)Tv[12]);
            float tr = (float)Tv[4] + (float)Tv[8] + (float)Tv[12];
            float n2 = vx * vx + vy * vy + vz * vz;
            float sum_uv = (s - n2 * (1.0f / 3.0f) * tr) * (inv_d * inv_d);

            Eelec += qu * sum_uv * chi3;
            out[e] = (d <= CUTOFF) ? (KEHALF * Eelec) : 0.0f;
        }
    }
}

// ---- Fallback (ws too small): direct scalar-gather kernel ----
__global__ __launch_bounds__(256)
void damped_elec_direct(const float* __restrict__ dist,
                        const float* __restrict__ vec,
                        const float* __restrict__ q,
                        const float* __restrict__ mu,
                        const float* __restrict__ quad,
                        const int* __restrict__ idx_u,
                        const int* __restrict__ idx_v,
                        float* __restrict__ out, int E) {
    int e = blockIdx.x * blockDim.x + threadIdx.x;
    if (e >= E) return;
    float d = dist[e];
    int u = idx_u[e], v = idx_v[e];
    float vx = vec[3 * e + 0], vy = vec[3 * e + 1], vz = vec[3 * e + 2];

    float inv_d = 1.0f / d;
    float x = fminf(fmaxf(d * 0.5f, 0.0f), 1.0f);
    float x2 = x * x, x3 = x2 * x;
    float sw = 1.0f - x3 * (10.0f - 15.0f * x + 6.0f * x2);
    float chi = sw / sqrtf(d * d + 1.0f) + (1.0f - sw) * inv_d;
    float chi2 = chi * chi, chi3 = chi2 * chi;

    float qu = q[u], qv = q[v];
    const float* mu_u = mu + 3 * u;
    const float* mu_v = mu + 3 * v;
    float dot_uv = (vx * mu_v[0] + vy * mu_v[1] + vz * mu_v[2]) * inv_d;
    float dot_vu = (vx * mu_u[0] + vy * mu_u[1] + vz * mu_u[2]) * inv_d;
    float mudot  = mu_u[0] * mu_v[0] + mu_u[1] * mu_v[1] + mu_u[2] * mu_v[2];

    float Eelec = qu * qv * chi
                + 2.0f * qu * dot_uv * chi2
                + (mudot - 3.0f * dot_uv * dot_vu) * chi3;

    const float* Qv = quad + 9 * v;
    float s = vx * (vx * Qv[0] + vy * Qv[1] + vz * Qv[2])
            + vy * (vx * Qv[3] + vy * Qv[4] + vz * Qv[5])
            + vz * (vx * Qv[6] + vy * Qv[7] + vz * Qv[8]);
    float tr = Qv[0] + Qv[4] + Qv[8];
    float n2 = vx * vx + vy * vy + vz * vz;
    float sum_uv = (s - n2 * (1.0f / 3.0f) * tr) * (inv_d * inv_d);

    Eelec += qu * sum_uv * chi3;
    out[e] = (d <= CUTOFF) ? (KEHALF * Eelec) : 0.0f;
}

extern "C" void kernel_launch(void* const* d_in, const int* in_sizes, int n_in,
                              void* d_out, int out_size, void* d_ws, size_t ws_size,
                              hipStream_t stream) {
    const float* dist  = (const float*)d_in[0];
    const float* vec   = (const float*)d_in[1];
    const float* q     = (const float*)d_in[2];
    const float* mu    = (const float*)d_in[3];
    const float* quad  = (const float*)d_in[4];
    const int*   idx_u = (const int*)d_in[5];
    const int*   idx_v = (const int*)d_in[6];
    float* out = (float*)d_out;

    int E = in_sizes[0];
    int N = in_sizes[2];  // atomic_charges count == N_ATOMS

    size_t need = (size_t)N * 16 * sizeof(_Float16);
    if (ws_size >= need) {
        _Float16* T = (_Float16*)d_ws;
        pack_atoms_half<<<(N + 255) / 256, 256, 0, stream>>>(q, mu, quad, T, N);
        int threads = (E + 3) / 4;
        damped_elec_h<<<(threads + 255) / 256, 256, 0, stream>>>(
            dist, vec, T, idx_u, idx_v, out, E);
    } else {
        damped_elec_direct<<<(E + 255) / 256, 256, 0, stream>>>(
            dist, vec, q, mu, quad, idx_u, idx_v, out, E);
    }
}

// Round 6
// 146.865 us; speedup vs baseline: 1.4237x; 1.1171x over previous
//
#include <hip/hip_runtime.h>

#define KEHALF 7.199822675975274f
#define CUTOFF 12.0f

typedef float    fx4 __attribute__((ext_vector_type(4)));
typedef int      ix4 __attribute__((ext_vector_type(4)));
typedef int      ix2 __attribute__((ext_vector_type(2)));
typedef _Float16 hx4 __attribute__((ext_vector_type(4)));
typedef _Float16 hx8 __attribute__((ext_vector_type(8)));

static __device__ __forceinline__ hx4 as_h4(ix2 v) { union { ix2 i; hx4 h; } u; u.i = v; return u.h; }
static __device__ __forceinline__ hx8 as_h8(ix4 v) { union { ix4 i; hx8 h; } u; u.i = v; return u.h; }

// ---- Pack kernel: T[atom] = 16 halves (32B): [q, mu(3), Q(9), pad(3)] ----
// Table = 100K * 32B = 3.2 MB -> fits a 4 MB per-XCD L2.
__global__ __launch_bounds__(256)
void pack_atoms_half(const float* __restrict__ q,
                     const float* __restrict__ mu,
                     const float* __restrict__ quad,
                     _Float16* __restrict__ T, int N) {
    int a = blockIdx.x * blockDim.x + threadIdx.x;
    if (a >= N) return;
    const float* m = mu + 3 * a;
    const float* Q = quad + 9 * a;
    hx8 t0, t1;
    t0[0] = (_Float16)q[a];
    t0[1] = (_Float16)m[0]; t0[2] = (_Float16)m[1]; t0[3] = (_Float16)m[2];
    t0[4] = (_Float16)Q[0]; t0[5] = (_Float16)Q[1]; t0[6] = (_Float16)Q[2]; t0[7] = (_Float16)Q[3];
    t1[0] = (_Float16)Q[4]; t1[1] = (_Float16)Q[5]; t1[2] = (_Float16)Q[6]; t1[3] = (_Float16)Q[7];
    t1[4] = (_Float16)Q[8]; t1[5] = (_Float16)0.0f; t1[6] = (_Float16)0.0f; t1[7] = (_Float16)0.0f;
    hx8* dst = reinterpret_cast<hx8*>(T + 16 * a);
    dst[0] = t0; dst[1] = t1;
}

// ---- Main kernel: fp16-table gathers, ALL loads forced into one window ----
__global__ __launch_bounds__(256)
void damped_elec_h(const float* __restrict__ dist,
                   const float* __restrict__ vec,
                   const _Float16* __restrict__ T,
                   const int* __restrict__ idx_u,
                   const int* __restrict__ idx_v,
                   float* __restrict__ out, int E) {
    int t = blockIdx.x * blockDim.x + threadIdx.x;
    int e0 = t * 4;
    if (e0 >= E) return;

    if (e0 + 4 <= E) {
        // Indices first (gather addresses depend on them).
        ix4 u4 = __builtin_nontemporal_load(reinterpret_cast<const ix4*>(idx_u + e0));
        ix4 v4 = __builtin_nontemporal_load(reinterpret_cast<const ix4*>(idx_v + e0));
        // Streaming loads (non-temporal: keep L2 for the atom table).
        fx4 d4 = __builtin_nontemporal_load(reinterpret_cast<const fx4*>(dist + e0));
        fx4 va = __builtin_nontemporal_load(reinterpret_cast<const fx4*>(vec + 3 * e0));
        fx4 vb = __builtin_nontemporal_load(reinterpret_cast<const fx4*>(vec + 3 * e0 + 4));
        fx4 vc = __builtin_nontemporal_load(reinterpret_cast<const fx4*>(vec + 3 * e0 + 8));

        int ub[4]  = {u4.x, u4.y, u4.z, u4.w};
        int vbi[4] = {v4.x, v4.y, v4.z, v4.w};

        // Gather phase: 3 loads per edge, issued back-to-back (int-typed for asm).
        ix2 gu[4];
        ix4 gv0[4], gv1[4];
#pragma unroll
        for (int k = 0; k < 4; ++k) {
            const _Float16* pu = T + ((long)ub[k] << 4);
            const _Float16* pv = T + ((long)vbi[k] << 4);
            gu[k]  = *reinterpret_cast<const ix2*>(pu);
            gv0[k] = *reinterpret_cast<const ix4*>(pv);
            gv1[k] = *reinterpret_cast<const ix4*>(pv + 8);
        }

        // Keep-live fence: force every load issued and materialized HERE,
        // so the scheduler cannot sink gathers into the compute loop
        // (one s_waitcnt drain instead of 4+ serialized windows).
        asm volatile("" : "+v"(d4), "+v"(va), "+v"(vb), "+v"(vc),
                          "+v"(gu[0]), "+v"(gu[1]), "+v"(gu[2]), "+v"(gu[3]),
                          "+v"(gv0[0]), "+v"(gv0[1]), "+v"(gv0[2]), "+v"(gv0[3]),
                          "+v"(gv1[0]), "+v"(gv1[1]), "+v"(gv1[2]), "+v"(gv1[3]));

        float db[4]  = {d4.x, d4.y, d4.z, d4.w};
        float vvv[12] = {va.x, va.y, va.z, va.w,
                         vb.x, vb.y, vb.z, vb.w,
                         vc.x, vc.y, vc.z, vc.w};

        // Compute phase (fp32).
        float res[4];
#pragma unroll
        for (int k = 0; k < 4; ++k) {
            float d = db[k];
            float vx = vvv[3 * k + 0], vy = vvv[3 * k + 1], vz = vvv[3 * k + 2];
            hx4 au  = as_h4(gu[k]);
            hx8 bv0 = as_h8(gv0[k]);
            hx8 bv1 = as_h8(gv1[k]);

            float inv_d = __builtin_amdgcn_rcpf(d);
            float x = fminf(fmaxf(d * 0.5f, 0.0f), 1.0f);
            float x2 = x * x;
            float x3 = x2 * x;
            float sw = 1.0f - x3 * (10.0f - 15.0f * x + 6.0f * x2);
            float chi = sw * __builtin_amdgcn_rsqf(d * d + 1.0f) + (1.0f - sw) * inv_d;
            float chi2 = chi * chi;
            float chi3 = chi2 * chi;

            float qu    = (float)au[0];
            float mux_u = (float)au[1], muy_u = (float)au[2], muz_u = (float)au[3];
            float qv    = (float)bv0[0];
            float mux_v = (float)bv0[1], muy_v = (float)bv0[2], muz_v = (float)bv0[3];
            float q00 = (float)bv0[4], q01 = (float)bv0[5], q02 = (float)bv0[6];
            float q10 = (float)bv0[7];
            float q11 = (float)bv1[0], q12 = (float)bv1[1], q20 = (float)bv1[2];
            float q21 = (float)bv1[3], q22 = (float)bv1[4];

            float dot_uv = (vx * mux_v + vy * muy_v + vz * muz_v) * inv_d;
            float dot_vu = (vx * mux_u + vy * muy_u + vz * muz_u) * inv_d;
            float mudot  = mux_u * mux_v + muy_u * muy_v + muz_u * muz_v;

            float Eelec = qu * qv * chi
                        + 2.0f * qu * dot_uv * chi2
                        + (mudot - 3.0f * dot_uv * dot_vu) * chi3;

            float s = vx * (vx * q00 + vy * q01 + vz * q02)
                    + vy * (vx * q10 + vy * q11 + vz * q12)
                    + vz * (vx * q20 + vy * q21 + vz * q22);
            float tr = q00 + q11 + q22;
            float n2 = vx * vx + vy * vy + vz * vz;
            float sum_uv = (s - n2 * (1.0f / 3.0f) * tr) * (inv_d * inv_d);

            Eelec += qu * sum_uv * chi3;
            res[k] = (d <= CUTOFF) ? (KEHALF * Eelec) : 0.0f;
        }
        fx4 o4 = {res[0], res[1], res[2], res[3]};
        __builtin_nontemporal_store(o4, reinterpret_cast<fx4*>(out + e0));
    } else {
        // Scalar tail.
        for (int e = e0; e < E; ++e) {
            float d = dist[e];
            int u = idx_u[e], v = idx_v[e];
            float vx = vec[3 * e + 0], vy = vec[3 * e + 1], vz = vec[3 * e + 2];
            const _Float16* Tu = T + ((long)u << 4);
            const _Float16* Tv = T + ((long)v << 4);

            float inv_d = 1.0f / d;
            float x = fminf(fmaxf(d * 0.5f, 0.0f), 1.0f);
            float x2 = x * x, x3 = x2 * x;
            float sw = 1.0f - x3 * (10.0f - 15.0f * x + 6.0f * x2);
            float chi = sw / sqrtf(d * d + 1.0f) + (1.0f - sw) * inv_d;
            float chi2 = chi * chi, chi3 = chi2 * chi;

            float qu = (float)Tu[0], qv = (float)Tv[0];
            float dot_uv = (vx * (float)Tv[1] + vy * (float)Tv[2] + vz * (float)Tv[3]) * inv_d;
            float dot_vu = (vx * (float)Tu[1] + vy * (float)Tu[2] + vz * (float)Tu[3]) * inv_d;
            float mudot  = (float)Tu[1] * (float)Tv[1] + (float)Tu[2] * (float)Tv[2]
                         + (float)Tu[3] * (float)Tv[3];

            float Eelec = qu * qv * chi
                        + 2.0f * qu * dot_uv * chi2
                        + (mudot - 3.0f * dot_uv * dot_vu) * chi3;

            float s = vx * (vx * (float)Tv[4] + vy * (float)Tv[5] + vz * (float)Tv[6])
                    + vy * (vx * (float)Tv[7] + vy * (float)Tv[8] + vz * (float)Tv[9])
                    + vz * (vx * (float)Tv[10] + vy * (float)Tv[11] + vz * (float)Tv[12]);
            float tr = (float)Tv[4] + (float)Tv[8] + (float)Tv[12];
            float n2 = vx * vx + vy * vy + vz * vz;
            float sum_uv = (s - n2 * (1.0f / 3.0f) * tr) * (inv_d * inv_d);

            Eelec += qu * sum_uv * chi3;
            out[e] = (d <= CUTOFF) ? (KEHALF * Eelec) : 0.0f;
        }
    }
}

// ---- Fallback (ws too small): direct scalar-gather kernel ----
__global__ __launch_bounds__(256)
void damped_elec_direct(const float* __restrict__ dist,
                        const float* __restrict__ vec,
                        const float* __restrict__ q,
                        const float* __restrict__ mu,
                        const float* __restrict__ quad,
                        const int* __restrict__ idx_u,
                        const int* __restrict__ idx_v,
                        float* __restrict__ out, int E) {
    int e = blockIdx.x * blockDim.x + threadIdx.x;
    if (e >= E) return;
    float d = dist[e];
    int u = idx_u[e], v = idx_v[e];
    float vx = vec[3 * e + 0], vy = vec[3 * e + 1], vz = vec[3 * e + 2];

    float inv_d = 1.0f / d;
    float x = fminf(fmaxf(d * 0.5f, 0.0f), 1.0f);
    float x2 = x * x, x3 = x2 * x;
    float sw = 1.0f - x3 * (10.0f - 15.0f * x + 6.0f * x2);
    float chi = sw / sqrtf(d * d + 1.0f) + (1.0f - sw) * inv_d;
    float chi2 = chi * chi, chi3 = chi2 * chi;

    float qu = q[u], qv = q[v];
    const float* mu_u = mu + 3 * u;
    const float* mu_v = mu + 3 * v;
    float dot_uv = (vx * mu_v[0] + vy * mu_v[1] + vz * mu_v[2]) * inv_d;
    float dot_vu = (vx * mu_u[0] + vy * mu_u[1] + vz * mu_u[2]) * inv_d;
    float mudot  = mu_u[0] * mu_v[0] + mu_u[1] * mu_v[1] + mu_u[2] * mu_v[2];

    float Eelec = qu * qv * chi
                + 2.0f * qu * dot_uv * chi2
                + (mudot - 3.0f * dot_uv * dot_vu) * chi3;

    const float* Qv = quad + 9 * v;
    float s = vx * (vx * Qv[0] + vy * Qv[1] + vz * Qv[2])
            + vy * (vx * Qv[3] + vy * Qv[4] + vz * Qv[5])
            + vz * (vx * Qv[6] + vy * Qv[7] + vz * Qv[8]);
    float tr = Qv[0] + Qv[4] + Qv[8];
    float n2 = vx * vx + vy * vy + vz * vz;
    float sum_uv = (s - n2 * (1.0f / 3.0f) * tr) * (inv_d * inv_d);

    Eelec += qu * sum_uv * chi3;
    out[e] = (d <= CUTOFF) ? (KEHALF * Eelec) : 0.0f;
}

extern "C" void kernel_launch(void* const* d_in, const int* in_sizes, int n_in,
                              void* d_out, int out_size, void* d_ws, size_t ws_size,
                              hipStream_t stream) {
    const float* dist  = (const float*)d_in[0];
    const float* vec   = (const float*)d_in[1];
    const float* q     = (const float*)d_in[2];
    const float* mu    = (const float*)d_in[3];
    const float* quad  = (const float*)d_in[4];
    const int*   idx_u = (const int*)d_in[5];
    const int*   idx_v = (const int*)d_in[6];
    float* out = (float*)d_out;

    int E = in_sizes[0];
    int N = in_sizes[2];  // atomic_charges count == N_ATOMS

    size_t need = (size_t)N * 16 * sizeof(_Float16);
    if (ws_size >= need) {
        _Float16* T = (_Float16*)d_ws;
        pack_atoms_half<<<(N + 255) / 256, 256, 0, stream>>>(q, mu, quad, T, N);
        int threads = (E + 3) / 4;
        damped_elec_h<<<(threads + 255) / 256, 256, 0, stream>>>(
            dist, vec, T, idx_u, idx_v, out, E);
    } else {
        damped_elec_direct<<<(E + 255) / 256, 256, 0, stream>>>(
            dist, vec, q, mu, quad, idx_u, idx_v, out, E);
    }
}